// Round 7
// baseline (803.169 us; speedup 1.0000x reference)
//
#include <hip/hip_runtime.h>
#include <stdint.h>

#define REG_P   0.05f
#define LOG2E   1.4426950408889634f
#define LN2     0.6931471805599453f
#define NSPLIT  8

typedef int   int32x8 __attribute__((ext_vector_type(8)));
typedef float floatx4 __attribute__((ext_vector_type(4)));

__device__ inline int32x8 load32B(const void* p) {
    union { int32x8 v; uint4 q[2]; } u;
    u.q[0] = ((const uint4*)p)[0];
    u.q[1] = ((const uint4*)p)[1];
    return u.v;
}

// block-wide sum of v[0..M): float4 grid-stride + wave butterfly + LDS.
__device__ inline float block_sum_f(const float* __restrict__ v, int M, int tid,
                                    float* redbuf) {
    float s = 0.f;
    const float4* v4 = (const float4*)v;
    for (int j = tid; j < (M >> 2); j += 256) {
        float4 q = v4[j];
        s += (q.x + q.y) + (q.z + q.w);
    }
    #pragma unroll
    for (int mask = 1; mask < 64; mask <<= 1) s += __shfl_xor(s, mask, 64);
    int wv = tid >> 6, lane = tid & 63;
    if (lane == 0) redbuf[wv] = s;
    __syncthreads();
    return (redbuf[0] + redbuf[1]) + (redbuf[2] + redbuf[3]);
}

// k1: pack fp32 -> fp8 e4m3 (hw cvt) + per-row fp32 squared norms.
// 256 thr = 16 rows x 16 chunks of 8 values. S -> row-major Sb8 (128 B/row).
// T -> fragment-ordered Tbs8: tile t (64 cols), chunk (ct,quad,l16) at
//   t*8192 + (ct*64 + quad*16 + l16)*32 holds T[t*64+ct*16+l16][quad*32..+31].
// Block 0 zero-inits d_out (k4 accumulates into it; stream order guarantees).
__global__ void k1_pack(const float* __restrict__ src, const float* __restrict__ tgt,
                        unsigned char* __restrict__ Sb8, unsigned char* __restrict__ Tbs8,
                        float* __restrict__ sx2, float* __restrict__ ty2,
                        float* __restrict__ out, int N, int M) {
    int tid = threadIdx.x;
    if (blockIdx.x == 0 && tid == 0) out[0] = 0.0f;
    int r16 = tid >> 4;
    int c8  = tid & 15;
    int row_id = blockIdx.x * 16 + r16;
    bool isS = row_id < N;
    int row = isS ? row_id : row_id - N;
    const float4* sp = (const float4*)((isS ? src : tgt) + (size_t)row * 128 + c8 * 8);
    float4 f0 = sp[0], f1 = sp[1];
    int w0 = 0, w1 = 0;
    w0 = __builtin_amdgcn_cvt_pk_fp8_f32(f0.x, f0.y, w0, false);
    w0 = __builtin_amdgcn_cvt_pk_fp8_f32(f0.z, f0.w, w0, true);
    w1 = __builtin_amdgcn_cvt_pk_fp8_f32(f1.x, f1.y, w1, false);
    w1 = __builtin_amdgcn_cvt_pk_fp8_f32(f1.z, f1.w, w1, true);
    uint2 val = make_uint2((unsigned)w0, (unsigned)w1);
    float sq = f0.x*f0.x + f0.y*f0.y + f0.z*f0.z + f0.w*f0.w
             + f1.x*f1.x + f1.y*f1.y + f1.z*f1.z + f1.w*f1.w;
    #pragma unroll
    for (int mask = 1; mask < 16; mask <<= 1) sq += __shfl_xor(sq, mask, 16);
    if (isS) {
        ((uint2*)(Sb8 + (size_t)row * 128 + c8 * 8))[0] = val;
        if (c8 == 0) sx2[row] = sq;
    } else {
        int t = row >> 6, jc = row & 63;
        int ct = jc >> 4, l16 = jc & 15;
        int quad = c8 >> 2, rem = c8 & 3;
        size_t dst = (size_t)t * 8192 + (size_t)((ct * 64 + quad * 16 + l16) * 32 + rem * 8);
        ((uint2*)(Tbs8 + dst))[0] = val;
        if (c8 == 0) ty2[row] = sq;
    }
}

// k3: l_i = sum_j exp2(b2_j + a2*dot_ij) via MX-fp8 MFMA (16x16x128, scales=1.0).
// No max shift: exponent in [-92,+33], fp32-safe.
// R16: content-floor cleanup. Empirical law from R10/R12/R14/R15: wall tracks
// per-wave instruction content 1:1 (occupancy/slack/bytes-invariant; trans ~8cy
// so poly hurt). Changes vs R14: (a) ping-pong 2-chunk body -> P/Q register
// roles alternate, eliminating the 8 v_mov/chunk lag-copies; (b) rcp stagger
// deleted (null); (c) poly reverted (regression). Kept: depth-3 bq rotation
// (indices compile-time under unroll 2, period-2 mod-4 pattern), lag-1 exp,
// lpart [split][row]. Geometry: NSPLIT=8, grid 1024, launch_bounds(256,4).
__global__ __launch_bounds__(256, 4) void k3_main(
    const unsigned char* __restrict__ Sb8, const unsigned char* __restrict__ Tbs8,
    const float* __restrict__ psi, const float* __restrict__ ty2,
    float* __restrict__ lpart, int N, int M) {
    __shared__ float sb2a[1024];
    __shared__ float redA[4];
    const int tid  = threadIdx.x;
    const int lane = tid & 63;
    const int wv   = tid >> 6;
    const int quad = lane >> 4, l16 = lane & 15;
    const int b = blockIdx.x;
    const int split = b & 7;
    const int i0 = (b >> 3) * 128;
    const int mspan = M / NSPLIT;            // 1024
    const int jstart = split * mspan;

    float ty2sum = block_sum_f(ty2, M, tid, redA);   // includes one barrier
    float scale = ty2sum / (float)M;
    float c1 = 1.0f / (REG_P * scale);
    float a2 = 2.0f * LOG2E / (REG_P * scale);

    for (int idx = tid; idx < mspan; idx += 256) {
        int j = jstart + idx;
        sb2a[idx] = (psi[j] * (1.0f / REG_P) - ty2[j] * c1) * LOG2E;
    }
    __syncthreads();                          // last barrier

    // A fragments: rows i0 + wv*32 + rt*16 + l16, k-bytes [quad*32, +32)
    int32x8 afrag[2];
    #pragma unroll
    for (int rt = 0; rt < 2; ++rt)
        afrag[rt] = load32B(Sb8 + (size_t)(i0 + wv * 32 + rt * 16 + l16) * 128 + quad * 32);

    float ls[2][4];
    #pragma unroll
    for (int rt = 0; rt < 2; ++rt)
        #pragma unroll
        for (int r = 0; r < 4; ++r) ls[rt][r] = 0.0f;

    const unsigned char* gb = Tbs8 + (size_t)jstart * 128 + (size_t)lane * 32;
    const floatx4 zero4 = (floatx4){0.f, 0.f, 0.f, 0.f};
    const int SC = 0x7F7F7F7F;               // E8M0 1.0 in every byte

    // depth-3 rotation: slot c&3 holds chunk c; loads run 3 chunks ahead
    int32x8 bq[4];
    bq[0] = load32B(gb);
    bq[1] = load32B(gb + 2048);
    bq[2] = load32B(gb + 4096);

    // prologue: chunk 0 MFMAs into P
    floatx4 p0 = __builtin_amdgcn_mfma_scale_f32_16x16x128_f8f6f4(
        afrag[0], bq[0], zero4, 0, 0, 0, SC, 0, SC);
    floatx4 p1 = __builtin_amdgcn_mfma_scale_f32_16x16x128_f8f6f4(
        afrag[1], bq[0], zero4, 0, 0, 0, SC, 0, SC);
    bq[3] = load32B(gb + 3 * 2048);
    float bvP = sb2a[0 * 16 + l16];
    float bvQ;
    floatx4 q0, q1;

    // body: g handles chunks 2g+1 (into Q, exp of P=chunk 2g) and
    //                       2g+2 (into P, exp of Q=chunk 2g+1). No lag copies.
    // bq slot indices (2g+1)&3, (2g+2)&3, (2g+4)&3, (2g+5)&3 have period 2 in g
    // -> compile-time under unroll 2.
    #pragma unroll 2
    for (int g = 0; g < 31; ++g) {
        q0 = __builtin_amdgcn_mfma_scale_f32_16x16x128_f8f6f4(
            afrag[0], bq[(2 * g + 1) & 3], zero4, 0, 0, 0, SC, 0, SC);
        q1 = __builtin_amdgcn_mfma_scale_f32_16x16x128_f8f6f4(
            afrag[1], bq[(2 * g + 1) & 3], zero4, 0, 0, 0, SC, 0, SC);
        bq[(2 * g + 4) & 3] = load32B(gb + (size_t)(2 * g + 4) * 2048);
        bvQ = sb2a[(2 * g + 1) * 16 + l16];
        #pragma unroll
        for (int r = 0; r < 4; ++r) {        // exp of chunk 2g (P)
            ls[0][r] += __builtin_amdgcn_exp2f(fmaf(a2, p0[r], bvP));
            ls[1][r] += __builtin_amdgcn_exp2f(fmaf(a2, p1[r], bvP));
        }
        p0 = __builtin_amdgcn_mfma_scale_f32_16x16x128_f8f6f4(
            afrag[0], bq[(2 * g + 2) & 3], zero4, 0, 0, 0, SC, 0, SC);
        p1 = __builtin_amdgcn_mfma_scale_f32_16x16x128_f8f6f4(
            afrag[1], bq[(2 * g + 2) & 3], zero4, 0, 0, 0, SC, 0, SC);
        bq[(2 * g + 5) & 3] = load32B(gb + (size_t)(2 * g + 5) * 2048);  // <=4KB OOB in ws slack
        bvP = sb2a[(2 * g + 2) * 16 + l16];
        #pragma unroll
        for (int r = 0; r < 4; ++r) {        // exp of chunk 2g+1 (Q)
            ls[0][r] += __builtin_amdgcn_exp2f(fmaf(a2, q0[r], bvQ));
            ls[1][r] += __builtin_amdgcn_exp2f(fmaf(a2, q1[r], bvQ));
        }
    }
    // tail: chunk 63 into Q, exp of chunk 62 (P), then exp of chunk 63 (Q)
    q0 = __builtin_amdgcn_mfma_scale_f32_16x16x128_f8f6f4(
        afrag[0], bq[63 & 3], zero4, 0, 0, 0, SC, 0, SC);
    q1 = __builtin_amdgcn_mfma_scale_f32_16x16x128_f8f6f4(
        afrag[1], bq[63 & 3], zero4, 0, 0, 0, SC, 0, SC);
    bvQ = sb2a[63 * 16 + l16];
    #pragma unroll
    for (int r = 0; r < 4; ++r) {
        ls[0][r] += __builtin_amdgcn_exp2f(fmaf(a2, p0[r], bvP));
        ls[1][r] += __builtin_amdgcn_exp2f(fmaf(a2, p1[r], bvP));
    }
    #pragma unroll
    for (int r = 0; r < 4; ++r) {
        ls[0][r] += __builtin_amdgcn_exp2f(fmaf(a2, q0[r], bvQ));
        ls[1][r] += __builtin_amdgcn_exp2f(fmaf(a2, q1[r], bvQ));
    }

    // sum over the 16 lanes (l16) sharing each row; lpart is [split][row]
    #pragma unroll
    for (int rt = 0; rt < 2; ++rt)
        #pragma unroll
        for (int r = 0; r < 4; ++r) {
            float v = ls[rt][r];
            #pragma unroll
            for (int mask = 1; mask < 16; mask <<= 1) v += __shfl_xor(v, mask, 64);
            if (l16 == 0) {
                int rowg = i0 + wv * 32 + rt * 16 + quad * 4 + r;
                lpart[(size_t)split * N + rowg] = v;
            }
        }
}

// k4: one row per thread. lpart is [split][row] -> 8 coalesced strided loads.
__global__ void k4_reduce(const float* __restrict__ lpart,
                          const float* __restrict__ sx2,
                          const float* __restrict__ psi,
                          const float* __restrict__ ty2,
                          float* __restrict__ out, int N, int M) {
    __shared__ float redA[4];
    __shared__ float redB[4];
    int tid = threadIdx.x;
    float ty2s = block_sum_f(ty2, M, tid, redA);
    float scale = ty2s / (float)M;

    int i = blockIdx.x * 256 + tid;
    float s = 0.f;
    #pragma unroll
    for (int p = 0; p < NSPLIT; ++p) s += lpart[(size_t)p * N + i];
    float L2 = __builtin_amdgcn_logf(s);     // v_log_f32 = log2
    float t = (-REG_P * LN2 * L2 + sx2[i] / scale) * (1.0f / (float)N);
    if (i < M) t += psi[i] * (1.0f / (float)M);
    #pragma unroll
    for (int mask = 1; mask < 64; mask <<= 1) t += __shfl_xor(t, mask, 64);
    int wv = tid >> 6, lane = tid & 63;
    if (lane == 0) redB[wv] = t;
    __syncthreads();
    if (tid == 0) {
        float total = (redB[0] + redB[1]) + (redB[2] + redB[3]);
        if (blockIdx.x == 0) total += REG_P * logf((float)M);
        atomicAdd(out, total);
    }
}

extern "C" void kernel_launch(void* const* d_in, const int* in_sizes, int n_in,
                              void* d_out, int out_size, void* d_ws, size_t ws_size,
                              hipStream_t stream) {
    const float* src = (const float*)d_in[0];
    const float* tgt = (const float*)d_in[1];
    const float* psi = (const float*)d_in[2];
    const int D = 128;
    const int N = in_sizes[0] / D;   // 16384
    const int M = in_sizes[1] / D;   // 8192

    char* ws = (char*)d_ws;
    float* sx2   = (float*)ws;
    float* ty2   = (float*)(ws + (size_t)N * 4);
    float* lpart = (float*)(ws + (size_t)N * 4 + (size_t)M * 4);
    size_t off = (size_t)N * 4 + (size_t)M * 4 + (size_t)N * NSPLIT * 4;
    off = (off + 255) & ~(size_t)255;
    unsigned char* Sb8  = (unsigned char*)(ws + off);
    unsigned char* Tbs8 = Sb8 + (size_t)N * 128;   // 1 MB Tbs8; >4KB ws slack after

    k1_pack<<<(N + M) / 16, 256, 0, stream>>>(src, tgt, Sb8, Tbs8, sx2, ty2,
                                              (float*)d_out, N, M);
    k3_main<<<(N / 128) * NSPLIT, 256, 0, stream>>>(Sb8, Tbs8, psi, ty2, lpart, N, M);
    k4_reduce<<<N / 256, 256, 0, stream>>>(lpart, sx2, psi, ty2, (float*)d_out, N, M);
}

// Round 8
// 96.457 us; speedup vs baseline: 8.3267x; 8.3267x over previous
//
#include <hip/hip_runtime.h>
#include <stdint.h>

#define REG_P   0.05f
#define LOG2E   1.4426950408889634f
#define LN2     0.6931471805599453f
#define NSPLIT  8

typedef int   int32x8 __attribute__((ext_vector_type(8)));
typedef float floatx4 __attribute__((ext_vector_type(4)));

__device__ inline int32x8 load32B(const void* p) {
    union { int32x8 v; uint4 q[2]; } u;
    u.q[0] = ((const uint4*)p)[0];
    u.q[1] = ((const uint4*)p)[1];
    return u.v;
}

// block-wide sum of v[0..M): float4 grid-stride + wave butterfly + LDS.
// All 256 threads return the exact total. Uses redbuf[4]; one internal barrier.
__device__ inline float block_sum_f(const float* __restrict__ v, int M, int tid,
                                    float* redbuf) {
    float s = 0.f;
    const float4* v4 = (const float4*)v;
    for (int j = tid; j < (M >> 2); j += 256) {
        float4 q = v4[j];
        s += (q.x + q.y) + (q.z + q.w);
    }
    #pragma unroll
    for (int mask = 1; mask < 64; mask <<= 1) s += __shfl_xor(s, mask, 64);
    int wv = tid >> 6, lane = tid & 63;
    if (lane == 0) redbuf[wv] = s;
    __syncthreads();
    return (redbuf[0] + redbuf[1]) + (redbuf[2] + redbuf[3]);
}

// k1: pack fp32 -> fp8 e4m3 (hw cvt) + per-row fp32 squared norms.
// 256 thr = 16 rows x 16 chunks of 8 values. S -> row-major Sb8 (128 B/row).
// T -> fragment-ordered Tbs8: tile t (64 cols), chunk (ct,quad,l16) at
//   t*8192 + (ct*64 + quad*16 + l16)*32 holds T[t*64+ct*16+l16][quad*32..+31].
// Block 0 zero-inits d_out (k4 accumulates into it; stream order guarantees).
__global__ void k1_pack(const float* __restrict__ src, const float* __restrict__ tgt,
                        unsigned char* __restrict__ Sb8, unsigned char* __restrict__ Tbs8,
                        float* __restrict__ sx2, float* __restrict__ ty2,
                        float* __restrict__ out, int N, int M) {
    int tid = threadIdx.x;
    if (blockIdx.x == 0 && tid == 0) out[0] = 0.0f;
    int r16 = tid >> 4;
    int c8  = tid & 15;
    int row_id = blockIdx.x * 16 + r16;
    bool isS = row_id < N;
    int row = isS ? row_id : row_id - N;
    const float4* sp = (const float4*)((isS ? src : tgt) + (size_t)row * 128 + c8 * 8);
    float4 f0 = sp[0], f1 = sp[1];
    int w0 = 0, w1 = 0;
    w0 = __builtin_amdgcn_cvt_pk_fp8_f32(f0.x, f0.y, w0, false);
    w0 = __builtin_amdgcn_cvt_pk_fp8_f32(f0.z, f0.w, w0, true);
    w1 = __builtin_amdgcn_cvt_pk_fp8_f32(f1.x, f1.y, w1, false);
    w1 = __builtin_amdgcn_cvt_pk_fp8_f32(f1.z, f1.w, w1, true);
    uint2 val = make_uint2((unsigned)w0, (unsigned)w1);
    float sq = f0.x*f0.x + f0.y*f0.y + f0.z*f0.z + f0.w*f0.w
             + f1.x*f1.x + f1.y*f1.y + f1.z*f1.z + f1.w*f1.w;
    #pragma unroll
    for (int mask = 1; mask < 16; mask <<= 1) sq += __shfl_xor(sq, mask, 16);
    if (isS) {
        ((uint2*)(Sb8 + (size_t)row * 128 + c8 * 8))[0] = val;
        if (c8 == 0) sx2[row] = sq;
    } else {
        int t = row >> 6, jc = row & 63;
        int ct = jc >> 4, l16 = jc & 15;
        int quad = c8 >> 2, rem = c8 & 3;
        size_t dst = (size_t)t * 8192 + (size_t)((ct * 64 + quad * 16 + l16) * 32 + rem * 8);
        ((uint2*)(Tbs8 + dst))[0] = val;
        if (c8 == 0) ty2[row] = sq;
    }
}

// k3: l_i = sum_j exp2(b2_j + a2*dot_ij) via MX-fp8 MFMA (16x16x128, scales=1.0).
// No max shift: exponent in [-92,+33], fp32-safe.
// Block = 4 waves x 32 rows = 128 rows, one M-split (1024 cols = 64 chunks of 16).
// Grid 1024 = 4 blocks/CU = 4 waves/SIMD (launch_bounds(256,4), ~95 VGPRs):
// TLP covers MFMA->exp2 and load latency — R9's 2-waves/SIMD was stall-bound.
// B: chunk-level rotation prefetch (distance 2), barrier-free K loop; prefetch
// reads up to 4KB past the split (inside ws slack, never consumed).
// Lag-1 epilogue: exp2 of chunk u-1 issues after MFMAs of chunk u.
// split = b&7 -> per-XCD hot B-slice = 128 KB (L2-resident).
// [R17: byte-exact restoration of the session-best kernel (96.3us). The
//  R10-R16 ledger: bytes/TLP/slack/convoy/trans-offload/mov-elim all null or
//  worse; k3 ~40us = instruction-content floor for this structure.]
__global__ __launch_bounds__(256, 4) void k3_main(
    const unsigned char* __restrict__ Sb8, const unsigned char* __restrict__ Tbs8,
    const float* __restrict__ psi, const float* __restrict__ ty2,
    float* __restrict__ lpart, int N, int M) {
    __shared__ float sb2a[1024];
    __shared__ float redA[4];
    const int tid  = threadIdx.x;
    const int lane = tid & 63;
    const int wv   = tid >> 6;
    const int quad = lane >> 4, l16 = lane & 15;
    const int b = blockIdx.x;
    const int split = b & 7;
    const int i0 = (b >> 3) * 128;
    const int mspan = M / NSPLIT;            // 1024
    const int jstart = split * mspan;

    float ty2sum = block_sum_f(ty2, M, tid, redA);   // includes one barrier
    float scale = ty2sum / (float)M;
    float c1 = 1.0f / (REG_P * scale);
    float a2 = 2.0f * LOG2E / (REG_P * scale);

    for (int idx = tid; idx < mspan; idx += 256) {
        int j = jstart + idx;
        sb2a[idx] = (psi[j] * (1.0f / REG_P) - ty2[j] * c1) * LOG2E;
    }
    __syncthreads();                          // last barrier

    // A fragments: rows i0 + wv*32 + rt*16 + l16, k-bytes [quad*32, +32)
    int32x8 afrag[2];
    #pragma unroll
    for (int rt = 0; rt < 2; ++rt)
        afrag[rt] = load32B(Sb8 + (size_t)(i0 + wv * 32 + rt * 16 + l16) * 128 + quad * 32);

    float ls[2][4];
    #pragma unroll
    for (int rt = 0; rt < 2; ++rt)
        #pragma unroll
        for (int r = 0; r < 4; ++r) ls[rt][r] = 0.0f;

    const unsigned char* gb = Tbs8 + (size_t)jstart * 128 + (size_t)lane * 32;
    const floatx4 zero4 = (floatx4){0.f, 0.f, 0.f, 0.f};
    const int SC = 0x7F7F7F7F;               // E8M0 1.0 in every byte

    int32x8 bc = load32B(gb);                // chunk 0
    int32x8 bn = load32B(gb + 2048);         // chunk 1
    floatx4 pA, pB;                          // lag-1 accumulators
    float bvP = 0.0f;

    #pragma unroll 4
    for (int u = 0; u < 64; ++u) {
        float bv = sb2a[u * 16 + l16];
        floatx4 c0 = __builtin_amdgcn_mfma_scale_f32_16x16x128_f8f6f4(
            afrag[0], bc, zero4, 0, 0, 0, SC, 0, SC);
        floatx4 c1v = __builtin_amdgcn_mfma_scale_f32_16x16x128_f8f6f4(
            afrag[1], bc, zero4, 0, 0, 0, SC, 0, SC);
        int32x8 bf = load32B(gb + (size_t)(u + 2) * 2048);  // <=4KB OOB, never used
        if (u) {
            #pragma unroll
            for (int r = 0; r < 4; ++r) {
                ls[0][r] += __builtin_amdgcn_exp2f(fmaf(a2, pA[r], bvP));
                ls[1][r] += __builtin_amdgcn_exp2f(fmaf(a2, pB[r], bvP));
            }
        }
        pA = c0; pB = c1v; bvP = bv;
        bc = bn; bn = bf;
    }
    #pragma unroll
    for (int r = 0; r < 4; ++r) {
        ls[0][r] += __builtin_amdgcn_exp2f(fmaf(a2, pA[r], bvP));
        ls[1][r] += __builtin_amdgcn_exp2f(fmaf(a2, pB[r], bvP));
    }

    // sum over the 16 lanes (l16) sharing each row
    #pragma unroll
    for (int rt = 0; rt < 2; ++rt)
        #pragma unroll
        for (int r = 0; r < 4; ++r) {
            float v = ls[rt][r];
            #pragma unroll
            for (int mask = 1; mask < 16; mask <<= 1) v += __shfl_xor(v, mask, 64);
            if (l16 == 0) {
                int rowg = i0 + wv * 32 + rt * 16 + quad * 4 + r;
                lpart[(size_t)rowg * NSPLIT + split] = v;
            }
        }
}

// k4: one row per thread. Self-computes ty2sum (scale). Per-row term:
//   (-REG*LN2*log2(sum_p lpart) + sx2[i]/scale) / N, plus psi[i]/M for i<M.
// Block reduce -> one atomicAdd into d_out. Block 0 adds REG*ln(M).
__global__ void k4_reduce(const float* __restrict__ lpart,
                          const float* __restrict__ sx2,
                          const float* __restrict__ psi,
                          const float* __restrict__ ty2,
                          float* __restrict__ out, int N, int M) {
    __shared__ float redA[4];
    __shared__ float redB[4];
    int tid = threadIdx.x;
    float ty2s = block_sum_f(ty2, M, tid, redA);
    float scale = ty2s / (float)M;

    int i = blockIdx.x * 256 + tid;
    const float4* lp = (const float4*)(lpart + (size_t)i * NSPLIT);
    float4 p0 = lp[0], p1 = lp[1];
    float s = (p0.x + p0.y + p0.z + p0.w) + (p1.x + p1.y + p1.z + p1.w);
    float L2 = __builtin_amdgcn_logf(s);     // v_log_f32 = log2
    float t = (-REG_P * LN2 * L2 + sx2[i] / scale) * (1.0f / (float)N);
    if (i < M) t += psi[i] * (1.0f / (float)M);
    #pragma unroll
    for (int mask = 1; mask < 64; mask <<= 1) t += __shfl_xor(t, mask, 64);
    int wv = tid >> 6, lane = tid & 63;
    if (lane == 0) redB[wv] = t;
    __syncthreads();
    if (tid == 0) {
        float total = (redB[0] + redB[1]) + (redB[2] + redB[3]);
        if (blockIdx.x == 0) total += REG_P * logf((float)M);
        atomicAdd(out, total);
    }
}

extern "C" void kernel_launch(void* const* d_in, const int* in_sizes, int n_in,
                              void* d_out, int out_size, void* d_ws, size_t ws_size,
                              hipStream_t stream) {
    const float* src = (const float*)d_in[0];
    const float* tgt = (const float*)d_in[1];
    const float* psi = (const float*)d_in[2];
    const int D = 128;
    const int N = in_sizes[0] / D;   // 16384
    const int M = in_sizes[1] / D;   // 8192

    char* ws = (char*)d_ws;
    float* sx2   = (float*)ws;
    float* ty2   = (float*)(ws + (size_t)N * 4);
    float* lpart = (float*)(ws + (size_t)N * 4 + (size_t)M * 4);
    size_t off = (size_t)N * 4 + (size_t)M * 4 + (size_t)N * NSPLIT * 4;
    off = (off + 255) & ~(size_t)255;
    unsigned char* Sb8  = (unsigned char*)(ws + off);
    unsigned char* Tbs8 = Sb8 + (size_t)N * 128;   // 1 MB Tbs8 + >4KB slack after

    k1_pack<<<(N + M) / 16, 256, 0, stream>>>(src, tgt, Sb8, Tbs8, sx2, ty2,
                                              (float*)d_out, N, M);
    k3_main<<<(N / 128) * NSPLIT, 256, 0, stream>>>(Sb8, Tbs8, psi, ty2, lpart, N, M);
    k4_reduce<<<N / 256, 256, 0, stream>>>(lpart, sx2, psi, ty2, (float*)d_out, N, M);
}